// Round 1
// baseline (173.325 us; speedup 1.0000x reference)
//
#include <hip/hip_runtime.h>
#include <hip/hip_bf16.h>

typedef __attribute__((ext_vector_type(8))) short short8v;
typedef __attribute__((ext_vector_type(4))) float f32x4;

#define L_SEQ 2048
#define D_DIM 1024
#define N_DIM 16
#define T_CHUNK 16
#define NCHUNK (L_SEQ / T_CHUNK)  // 128
#define EPS_DISC 1e-9f

__device__ __forceinline__ float softplusf(float x) {
    return (x > 15.f) ? x : __logf(1.f + __expf(x));
}

__device__ __forceinline__ unsigned short f2bf(float f) {
    unsigned int u = __float_as_uint(f);
    u += 0x7FFFu + ((u >> 16) & 1u);   // RNE
    return (unsigned short)(u >> 16);
}
__device__ __forceinline__ unsigned int pack2(float a, float b) {
    return (unsigned int)f2bf(a) | ((unsigned int)f2bf(b) << 16);
}

// ---------------- K1: h0 = init_w @ u_prefix + init_b  (16384 rows x 3072) ----
__global__ __launch_bounds__(256) void fm_h0_matvec(const float* __restrict__ init_w,
                                                    const float* __restrict__ init_b,
                                                    const float* __restrict__ u,
                                                    float* __restrict__ h0) {
    const int lane = threadIdx.x & 63;
    const int row  = blockIdx.x * 4 + (threadIdx.x >> 6);   // 4096 blocks * 4 waves
    const float4* w4 = (const float4*)(init_w + row * 3072);
    const float4* u4 = (const float4*)u;                    // u_prefix = first 3072 floats
    float acc = 0.f;
#pragma unroll
    for (int s = 0; s < 12; ++s) {
        float4 a = w4[s * 64 + lane];
        float4 b = u4[s * 64 + lane];
        acc += a.x * b.x + a.y * b.y + a.z * b.z + a.w * b.w;
    }
#pragma unroll
    for (int off = 32; off > 0; off >>= 1) acc += __shfl_down(acc, off);
    if (lane == 0) h0[row] = acc + init_b[row];
}

// ---------------- K2: dt = softplus(u @ dt_w^T + dt_b), bf16 MFMA GEMM --------
// M=2048(L) x N=1024(D) x K=1024.  BM=BN=128, BK=32, 4 waves (2x2), 64x64/wave.
__global__ __launch_bounds__(256) void fm_dt_gemm(const float* __restrict__ u,
                                                  const float* __restrict__ w,
                                                  const float* __restrict__ bias,
                                                  float* __restrict__ dt_out) {
    __shared__ unsigned int As[128 * 16];  // 128 rows x 32 bf16 (16 uints), swizzled
    __shared__ unsigned int Bs[128 * 16];
    const int t    = threadIdx.x;
    const int bm   = blockIdx.x;    // 0..15
    const int bn   = blockIdx.y;    // 0..7
    const int row  = t >> 1;        // 0..127
    const int half = t & 1;
    const int swz  = (row >> 1) & 3;
    const int lane = t & 63;
    const int wid  = t >> 6;
    const int wm   = wid >> 1, wn = wid & 1;
    const int lrow = lane & 15, lq = lane >> 4;

    const float* uptr = u + (bm * 128 + row) * 1024 + half * 16;
    const float* wptr = w + (bn * 128 + row) * 1024 + half * 16;

    f32x4 acc[4][4];
#pragma unroll
    for (int mi = 0; mi < 4; ++mi)
#pragma unroll
        for (int ni = 0; ni < 4; ++ni) acc[mi][ni] = (f32x4){0.f, 0.f, 0.f, 0.f};

    for (int k0 = 0; k0 < 1024; k0 += 32) {
        __syncthreads();
        {
            const float4* p = (const float4*)(uptr + k0);
            float4 a0 = p[0], a1 = p[1], a2 = p[2], a3 = p[3];
            uint4 c0 = make_uint4(pack2(a0.x, a0.y), pack2(a0.z, a0.w),
                                  pack2(a1.x, a1.y), pack2(a1.z, a1.w));
            uint4 c1 = make_uint4(pack2(a2.x, a2.y), pack2(a2.z, a2.w),
                                  pack2(a3.x, a3.y), pack2(a3.z, a3.w));
            const int kb0 = (half * 2) ^ swz, kb1 = (half * 2 + 1) ^ swz;
            *(uint4*)&As[row * 16 + kb0 * 4] = c0;
            *(uint4*)&As[row * 16 + kb1 * 4] = c1;

            const float4* q = (const float4*)(wptr + k0);
            float4 b0 = q[0], b1 = q[1], b2 = q[2], b3 = q[3];
            uint4 d0 = make_uint4(pack2(b0.x, b0.y), pack2(b0.z, b0.w),
                                  pack2(b1.x, b1.y), pack2(b1.z, b1.w));
            uint4 d1 = make_uint4(pack2(b2.x, b2.y), pack2(b2.z, b2.w),
                                  pack2(b3.x, b3.y), pack2(b3.z, b3.w));
            *(uint4*)&Bs[row * 16 + kb0 * 4] = d0;
            *(uint4*)&Bs[row * 16 + kb1 * 4] = d1;
        }
        __syncthreads();
        short8v af[4], bf[4];
#pragma unroll
        for (int mi = 0; mi < 4; ++mi) {
            const int ar = wm * 64 + mi * 16 + lrow;
            const int kb = lq ^ ((ar >> 1) & 3);
            af[mi] = *(const short8v*)&As[ar * 16 + kb * 4];
        }
#pragma unroll
        for (int ni = 0; ni < 4; ++ni) {
            const int br = wn * 64 + ni * 16 + lrow;
            const int kb = lq ^ ((br >> 1) & 3);
            bf[ni] = *(const short8v*)&Bs[br * 16 + kb * 4];
        }
#pragma unroll
        for (int mi = 0; mi < 4; ++mi)
#pragma unroll
            for (int ni = 0; ni < 4; ++ni)
                acc[mi][ni] = __builtin_amdgcn_mfma_f32_16x16x32_bf16(af[mi], bf[ni], acc[mi][ni], 0, 0, 0);
    }

#pragma unroll
    for (int mi = 0; mi < 4; ++mi)
#pragma unroll
        for (int ni = 0; ni < 4; ++ni) {
            const int cg = bn * 128 + wn * 64 + ni * 16 + lrow;
            const float bv = bias[cg];
#pragma unroll
            for (int j = 0; j < 4; ++j) {
                const int rg = bm * 128 + wm * 64 + mi * 16 + lq * 4 + j;
                dt_out[rg * 1024 + cg] = softplusf(acc[mi][ni][j] + bv);
            }
        }
}

// ---------------- K3: B = u@B_w^T + B_b, C = u@C_w^T + C_b  ([2048,16] each) --
__global__ __launch_bounds__(256) void fm_bc_gemv(const float* __restrict__ u,
                                                  const float* __restrict__ B_w,
                                                  const float* __restrict__ B_b,
                                                  const float* __restrict__ C_w,
                                                  const float* __restrict__ C_b,
                                                  float* __restrict__ Bout,
                                                  float* __restrict__ Cout) {
    const int tid = blockIdx.x * 256 + threadIdx.x;   // 65536 threads
    const int l = tid >> 5;
    const int col = tid & 31;
    const float* wrow = (col < 16) ? (B_w + col * 1024) : (C_w + (col - 16) * 1024);
    const float4* w4 = (const float4*)wrow;
    const float4* u4 = (const float4*)(u + l * 1024);
    float acc = 0.f;
#pragma unroll 8
    for (int j = 0; j < 256; ++j) {
        float4 a = u4[j], b = w4[j];
        acc += a.x * b.x + a.y * b.y + a.z * b.z + a.w * b.w;
    }
    if (col < 16) Bout[l * 16 + col] = acc + B_b[col];
    else          Cout[l * 16 + (col - 16)] = acc + C_b[col - 16];
}

// ---------------- K4: phase 1 — per-chunk (prod dA, local h with h_in=0) -----
__global__ __launch_bounds__(256) void fm_scan_phase1(const float* __restrict__ dt,
                                                      const float* __restrict__ Bm,
                                                      const float* __restrict__ u,
                                                      const float* __restrict__ A_log,
                                                      float* __restrict__ ap,
                                                      float* __restrict__ hl) {
    const int t = threadIdx.x;
    const int c = blockIdx.x >> 2;                 // 0..127
    const int d = ((blockIdx.x & 3) << 8) | t;     // 0..1023
    float An[16];
#pragma unroll
    for (int n = 0; n < 16; ++n) An[n] = -__expf(A_log[n]);
    float h[16], p[16];
#pragma unroll
    for (int n = 0; n < 16; ++n) { h[n] = 0.f; p[n] = 1.f; }

    const int l0 = c * T_CHUNK;
    for (int i = 0; i < T_CHUNK; ++i) {
        const int l = l0 + i;
        const float dtld = dt[l * D_DIM + d];
        const float uld  = u[l * D_DIM + d];
        const float4 b0 = *(const float4*)&Bm[l * 16 + 0];
        const float4 b1 = *(const float4*)&Bm[l * 16 + 4];
        const float4 b2 = *(const float4*)&Bm[l * 16 + 8];
        const float4 b3 = *(const float4*)&Bm[l * 16 + 12];
        auto body = [&](int n, float bn) {
            const float x = dtld * An[n];
            const float e = __expf(x);
            const float coef = (e - 1.f) * __builtin_amdgcn_rcpf(x + EPS_DISC);
            const float bu = coef * bn * uld;
            p[n] *= e;
            h[n] = fmaf(e, h[n], bu);
        };
        body(0, b0.x);  body(1, b0.y);  body(2, b0.z);  body(3, b0.w);
        body(4, b1.x);  body(5, b1.y);  body(6, b1.z);  body(7, b1.w);
        body(8, b2.x);  body(9, b2.y);  body(10, b2.z); body(11, b2.w);
        body(12, b3.x); body(13, b3.y); body(14, b3.z); body(15, b3.w);
    }
    const int base = c * (D_DIM * N_DIM) + d * 16;
    *(float4*)&ap[base + 0]  = make_float4(p[0], p[1], p[2], p[3]);
    *(float4*)&ap[base + 4]  = make_float4(p[4], p[5], p[6], p[7]);
    *(float4*)&ap[base + 8]  = make_float4(p[8], p[9], p[10], p[11]);
    *(float4*)&ap[base + 12] = make_float4(p[12], p[13], p[14], p[15]);
    *(float4*)&hl[base + 0]  = make_float4(h[0], h[1], h[2], h[3]);
    *(float4*)&hl[base + 4]  = make_float4(h[4], h[5], h[6], h[7]);
    *(float4*)&hl[base + 8]  = make_float4(h[8], h[9], h[10], h[11]);
    *(float4*)&hl[base + 12] = make_float4(h[12], h[13], h[14], h[15]);
}

// ---------------- K5: phase 2 — chunk-level scan; ap[c] overwritten w/ carry-in
__global__ __launch_bounds__(256) void fm_scan_phase2(const float* __restrict__ h0,
                                                      float* __restrict__ ap,
                                                      const float* __restrict__ hl) {
    const int tid = blockIdx.x * 256 + threadIdx.x;   // 0..16383 = d*16+n
    float h = h0[tid];
#pragma unroll 4
    for (int c = 0; c < NCHUNK; ++c) {
        const int idx = c * (D_DIM * N_DIM) + tid;
        const float a = ap[idx];
        const float b = hl[idx];
        ap[idx] = h;            // carry-in for phase 3
        h = fmaf(a, h, b);
    }
}

// ---------------- K6: phase 3 — recompute with carry-in, fuse C·h + epilogue --
__global__ __launch_bounds__(256) void fm_scan_phase3(const float* __restrict__ dt,
                                                      const float* __restrict__ Bm,
                                                      const float* __restrict__ Cm,
                                                      const float* __restrict__ u,
                                                      const float* __restrict__ A_log,
                                                      const float* __restrict__ hstart,
                                                      const float* __restrict__ D_w,
                                                      const float* __restrict__ scale,
                                                      float* __restrict__ out) {
    const int t = threadIdx.x;
    const int c = blockIdx.x >> 2;
    const int d = ((blockIdx.x & 3) << 8) | t;
    float An[16];
#pragma unroll
    for (int n = 0; n < 16; ++n) An[n] = -__expf(A_log[n]);
    float h[16];
    const int base = c * (D_DIM * N_DIM) + d * 16;
    {
        float4 h0v = *(const float4*)&hstart[base + 0];
        float4 h1v = *(const float4*)&hstart[base + 4];
        float4 h2v = *(const float4*)&hstart[base + 8];
        float4 h3v = *(const float4*)&hstart[base + 12];
        h[0] = h0v.x; h[1] = h0v.y; h[2] = h0v.z; h[3] = h0v.w;
        h[4] = h1v.x; h[5] = h1v.y; h[6] = h1v.z; h[7] = h1v.w;
        h[8] = h2v.x; h[9] = h2v.y; h[10] = h2v.z; h[11] = h2v.w;
        h[12] = h3v.x; h[13] = h3v.y; h[14] = h3v.z; h[15] = h3v.w;
    }
    const float scl = fmaxf(scale[0], 0.5f);
    const float dw = D_w[d];
    const int l0 = c * T_CHUNK;
    for (int i = 0; i < T_CHUNK; ++i) {
        const int l = l0 + i;
        const float dtld = dt[l * D_DIM + d];
        const float uld  = u[l * D_DIM + d];
        const float4 b0 = *(const float4*)&Bm[l * 16 + 0];
        const float4 b1 = *(const float4*)&Bm[l * 16 + 4];
        const float4 b2 = *(const float4*)&Bm[l * 16 + 8];
        const float4 b3 = *(const float4*)&Bm[l * 16 + 12];
        const float4 c0 = *(const float4*)&Cm[l * 16 + 0];
        const float4 c1 = *(const float4*)&Cm[l * 16 + 4];
        const float4 c2 = *(const float4*)&Cm[l * 16 + 8];
        const float4 c3 = *(const float4*)&Cm[l * 16 + 12];
        float y = 0.f;
        auto body = [&](int n, float bn, float cn) {
            const float x = dtld * An[n];
            const float e = __expf(x);
            const float coef = (e - 1.f) * __builtin_amdgcn_rcpf(x + EPS_DISC);
            const float bu = coef * bn * uld;
            h[n] = fmaf(e, h[n], bu);
            y = fmaf(cn, h[n], y);
        };
        body(0, b0.x, c0.x);   body(1, b0.y, c0.y);   body(2, b0.z, c0.z);   body(3, b0.w, c0.w);
        body(4, b1.x, c1.x);   body(5, b1.y, c1.y);   body(6, b1.z, c1.z);   body(7, b1.w, c1.w);
        body(8, b2.x, c2.x);   body(9, b2.y, c2.y);   body(10, b2.z, c2.z);  body(11, b2.w, c2.w);
        body(12, b3.x, c3.x);  body(13, b3.y, c3.y);  body(14, b3.z, c3.z);  body(15, b3.w, c3.w);
        y = fmaf(dw, uld, y);
        out[l * D_DIM + d] = softplusf(y) * scl;
    }
}

extern "C" void kernel_launch(void* const* d_in, const int* in_sizes, int n_in,
                              void* d_out, int out_size, void* d_ws, size_t ws_size,
                              hipStream_t stream) {
    const float* u      = (const float*)d_in[0];
    const float* A_log  = (const float*)d_in[1];
    const float* dt_w   = (const float*)d_in[2];
    const float* dt_b   = (const float*)d_in[3];
    const float* B_w    = (const float*)d_in[4];
    const float* B_b    = (const float*)d_in[5];
    const float* C_w    = (const float*)d_in[6];
    const float* C_b    = (const float*)d_in[7];
    const float* D_w    = (const float*)d_in[8];
    const float* scale  = (const float*)d_in[9];
    const float* init_w = (const float*)d_in[10];
    const float* init_b = (const float*)d_in[11];
    float* out = (float*)d_out;

    float* ws = (float*)d_ws;
    float* dt = ws;                                   // 2048*1024        = 2097152
    float* Bm = ws + 2097152;                         // 2048*16          = 32768
    float* Cm = ws + 2097152 + 32768;                 // 2048*16          = 32768
    float* h0 = ws + 2097152 + 65536;                 // 16384
    float* ap = ws + 2097152 + 65536 + 16384;         // 128*16384        = 2097152
    float* hl = ap + 2097152;                         // 128*16384        = 2097152

    hipLaunchKernelGGL(fm_h0_matvec, dim3(4096), dim3(256), 0, stream, init_w, init_b, u, h0);
    hipLaunchKernelGGL(fm_dt_gemm, dim3(16, 8), dim3(256), 0, stream, u, dt_w, dt_b, dt);
    hipLaunchKernelGGL(fm_bc_gemv, dim3(256), dim3(256), 0, stream, u, B_w, B_b, C_w, C_b, Bm, Cm);
    hipLaunchKernelGGL(fm_scan_phase1, dim3(512), dim3(256), 0, stream, dt, Bm, u, A_log, ap, hl);
    hipLaunchKernelGGL(fm_scan_phase2, dim3(64), dim3(256), 0, stream, h0, ap, hl);
    hipLaunchKernelGGL(fm_scan_phase3, dim3(512), dim3(256), 0, stream, dt, Bm, Cm, u, A_log, ap, D_w, scale, out);
}

// Round 2
// 120.283 us; speedup vs baseline: 1.4410x; 1.4410x over previous
//
#include <hip/hip_runtime.h>
#include <hip/hip_bf16.h>

typedef __attribute__((ext_vector_type(8))) short short8v;
typedef __attribute__((ext_vector_type(4))) float f32x4;

#define L_SEQ 2048
#define D_DIM 1024
#define N_DIM 16
#define T_CHUNK 32
#define NCHUNK (L_SEQ / T_CHUNK)  // 64
#define EPS_DISC 1e-9f

__device__ __forceinline__ float softplusf(float x) {
    return (x > 15.f) ? x : __logf(1.f + __expf(x));
}

__device__ __forceinline__ unsigned short f2bf(float f) {
    unsigned int u = __float_as_uint(f);
    u += 0x7FFFu + ((u >> 16) & 1u);   // RNE
    return (unsigned short)(u >> 16);
}
__device__ __forceinline__ unsigned int pack2(float a, float b) {
    return (unsigned int)f2bf(a) | ((unsigned int)f2bf(b) << 16);
}

// ============ K_A: fused parameter kernel ====================================
// blocks [0,128)    : dt = softplus(u @ dt_w^T + dt_b)   (bf16 MFMA GEMM)
// blocks [128,384)  : B = u@B_w^T+B_b ; C = u@C_w^T+C_b  (GEMV, L2-bound)
// blocks [384,4480) : h0 = init_w @ u_prefix + init_b    (HBM-bound matvec)
// GEMM/GEMV compute hides under the matvec's 192 MB HBM stream.
__global__ __launch_bounds__(256) void fm_params(const float* __restrict__ u,
                                                 const float* __restrict__ dt_w,
                                                 const float* __restrict__ dt_b,
                                                 const float* __restrict__ B_w,
                                                 const float* __restrict__ B_b,
                                                 const float* __restrict__ C_w,
                                                 const float* __restrict__ C_b,
                                                 const float* __restrict__ init_w,
                                                 const float* __restrict__ init_b,
                                                 float* __restrict__ dt_out,
                                                 float* __restrict__ Bout,
                                                 float* __restrict__ Cout,
                                                 float* __restrict__ h0) {
    __shared__ unsigned int As[128 * 16];
    __shared__ unsigned int Bs[128 * 16];
    const int b = blockIdx.x;
    const int t = threadIdx.x;

    if (b < 128) {
        // ---- dt GEMM: M=2048 x N=1024 x K=1024, BM=BN=128, BK=32 ----
        const int bm   = b & 15;
        const int bn   = b >> 4;
        const int row  = t >> 1;
        const int half = t & 1;
        const int swz  = (row >> 1) & 3;
        const int lane = t & 63;
        const int wid  = t >> 6;
        const int wm   = wid >> 1, wn = wid & 1;
        const int lrow = lane & 15, lq = lane >> 4;

        const float* uptr = u + (bm * 128 + row) * 1024 + half * 16;
        const float* wptr = dt_w + (bn * 128 + row) * 1024 + half * 16;

        f32x4 acc[4][4];
#pragma unroll
        for (int mi = 0; mi < 4; ++mi)
#pragma unroll
            for (int ni = 0; ni < 4; ++ni) acc[mi][ni] = (f32x4){0.f, 0.f, 0.f, 0.f};

        for (int k0 = 0; k0 < 1024; k0 += 32) {
            __syncthreads();
            {
                const float4* p = (const float4*)(uptr + k0);
                float4 a0 = p[0], a1 = p[1], a2 = p[2], a3 = p[3];
                uint4 c0 = make_uint4(pack2(a0.x, a0.y), pack2(a0.z, a0.w),
                                      pack2(a1.x, a1.y), pack2(a1.z, a1.w));
                uint4 c1 = make_uint4(pack2(a2.x, a2.y), pack2(a2.z, a2.w),
                                      pack2(a3.x, a3.y), pack2(a3.z, a3.w));
                const int kb0 = (half * 2) ^ swz, kb1 = (half * 2 + 1) ^ swz;
                *(uint4*)&As[row * 16 + kb0 * 4] = c0;
                *(uint4*)&As[row * 16 + kb1 * 4] = c1;

                const float4* q = (const float4*)(wptr + k0);
                float4 b0 = q[0], b1 = q[1], b2 = q[2], b3 = q[3];
                uint4 d0 = make_uint4(pack2(b0.x, b0.y), pack2(b0.z, b0.w),
                                      pack2(b1.x, b1.y), pack2(b1.z, b1.w));
                uint4 d1 = make_uint4(pack2(b2.x, b2.y), pack2(b2.z, b2.w),
                                      pack2(b3.x, b3.y), pack2(b3.z, b3.w));
                *(uint4*)&Bs[row * 16 + kb0 * 4] = d0;
                *(uint4*)&Bs[row * 16 + kb1 * 4] = d1;
            }
            __syncthreads();
            short8v af[4], bf[4];
#pragma unroll
            for (int mi = 0; mi < 4; ++mi) {
                const int ar = wm * 64 + mi * 16 + lrow;
                const int kb = lq ^ ((ar >> 1) & 3);
                af[mi] = *(const short8v*)&As[ar * 16 + kb * 4];
            }
#pragma unroll
            for (int ni = 0; ni < 4; ++ni) {
                const int br = wn * 64 + ni * 16 + lrow;
                const int kb = lq ^ ((br >> 1) & 3);
                bf[ni] = *(const short8v*)&Bs[br * 16 + kb * 4];
            }
#pragma unroll
            for (int mi = 0; mi < 4; ++mi)
#pragma unroll
                for (int ni = 0; ni < 4; ++ni)
                    acc[mi][ni] = __builtin_amdgcn_mfma_f32_16x16x32_bf16(af[mi], bf[ni], acc[mi][ni], 0, 0, 0);
        }

#pragma unroll
        for (int mi = 0; mi < 4; ++mi)
#pragma unroll
            for (int ni = 0; ni < 4; ++ni) {
                const int cg = bn * 128 + wn * 64 + ni * 16 + lrow;
                const float bv = dt_b[cg];
#pragma unroll
                for (int j = 0; j < 4; ++j) {
                    const int rg = bm * 128 + wm * 64 + mi * 16 + lq * 4 + j;
                    dt_out[rg * 1024 + cg] = softplusf(acc[mi][ni][j] + bv);
                }
            }
    } else if (b < 384) {
        // ---- B/C GEMV: [2048,16] each; w rows are L1/L2-resident ----
        const int tid = (b - 128) * 256 + t;   // 65536 threads
        const int l = tid >> 5;
        const int col = tid & 31;
        const float* wrow = (col < 16) ? (B_w + col * 1024) : (C_w + (col - 16) * 1024);
        const float4* w4 = (const float4*)wrow;
        const float4* u4 = (const float4*)(u + l * 1024);
        float acc = 0.f;
#pragma unroll 8
        for (int j = 0; j < 256; ++j) {
            float4 a = u4[j], bb = w4[j];
            acc += a.x * bb.x + a.y * bb.y + a.z * bb.z + a.w * bb.w;
        }
        if (col < 16) Bout[l * 16 + col] = acc + B_b[col];
        else          Cout[l * 16 + (col - 16)] = acc + C_b[col - 16];
    } else {
        // ---- h0 matvec: 16384 rows x 3072, one row per wave ----
        const int lane = t & 63;
        const int row  = (b - 384) * 4 + (t >> 6);
        const float4* w4 = (const float4*)(init_w + row * 3072);
        const float4* u4 = (const float4*)u;
        float acc = 0.f;
#pragma unroll
        for (int s = 0; s < 12; ++s) {
            float4 a = w4[s * 64 + lane];
            float4 bb = u4[s * 64 + lane];
            acc += a.x * bb.x + a.y * bb.y + a.z * bb.z + a.w * bb.w;
        }
#pragma unroll
        for (int off = 32; off > 0; off >>= 1) acc += __shfl_down(acc, off);
        if (lane == 0) h0[row] = acc + init_b[row];
    }
}

// ============ K_B: phase 1 — per-chunk (prod dA, local h with h_in=0) ========
__global__ __launch_bounds__(256) void fm_scan_phase1(const float* __restrict__ dt,
                                                      const float* __restrict__ Bm,
                                                      const float* __restrict__ u,
                                                      const float* __restrict__ A_log,
                                                      float* __restrict__ ap,
                                                      float* __restrict__ hl) {
    const int t = threadIdx.x;
    const int c = blockIdx.x >> 2;                 // 0..63
    const int d = ((blockIdx.x & 3) << 8) | t;     // 0..1023
    float An[16];
#pragma unroll
    for (int n = 0; n < 16; ++n) An[n] = -__expf(A_log[n]);
    float h[16], p[16];
#pragma unroll
    for (int n = 0; n < 16; ++n) { h[n] = 0.f; p[n] = 1.f; }

    const int l0 = c * T_CHUNK;
    for (int i = 0; i < T_CHUNK; ++i) {
        const int l = l0 + i;
        const float dtld = dt[l * D_DIM + d];
        const float uld  = u[l * D_DIM + d];
        const float4 b0 = *(const float4*)&Bm[l * 16 + 0];
        const float4 b1 = *(const float4*)&Bm[l * 16 + 4];
        const float4 b2 = *(const float4*)&Bm[l * 16 + 8];
        const float4 b3 = *(const float4*)&Bm[l * 16 + 12];
        auto body = [&](int n, float bn) {
            const float x = dtld * An[n];
            const float e = __expf(x);
            const float coef = (e - 1.f) * __builtin_amdgcn_rcpf(x + EPS_DISC);
            const float bu = coef * bn * uld;
            p[n] *= e;
            h[n] = fmaf(e, h[n], bu);
        };
        body(0, b0.x);  body(1, b0.y);  body(2, b0.z);  body(3, b0.w);
        body(4, b1.x);  body(5, b1.y);  body(6, b1.z);  body(7, b1.w);
        body(8, b2.x);  body(9, b2.y);  body(10, b2.z); body(11, b2.w);
        body(12, b3.x); body(13, b3.y); body(14, b3.z); body(15, b3.w);
    }
    const int base = c * (D_DIM * N_DIM) + d * 16;
    *(float4*)&ap[base + 0]  = make_float4(p[0], p[1], p[2], p[3]);
    *(float4*)&ap[base + 4]  = make_float4(p[4], p[5], p[6], p[7]);
    *(float4*)&ap[base + 8]  = make_float4(p[8], p[9], p[10], p[11]);
    *(float4*)&ap[base + 12] = make_float4(p[12], p[13], p[14], p[15]);
    *(float4*)&hl[base + 0]  = make_float4(h[0], h[1], h[2], h[3]);
    *(float4*)&hl[base + 4]  = make_float4(h[4], h[5], h[6], h[7]);
    *(float4*)&hl[base + 8]  = make_float4(h[8], h[9], h[10], h[11]);
    *(float4*)&hl[base + 12] = make_float4(h[12], h[13], h[14], h[15]);
}

// ============ K_C: phase 2 — chunk-level scan (64 steps) =====================
// 256 blocks x 64 threads -> one wave per CU, maximizes per-CU load concurrency.
__global__ __launch_bounds__(64) void fm_scan_phase2(const float* __restrict__ h0,
                                                     float* __restrict__ ap,
                                                     const float* __restrict__ hl) {
    const int tid = blockIdx.x * 64 + threadIdx.x;   // 0..16383 = d*16+n
    float h = h0[tid];
#pragma unroll 8
    for (int c = 0; c < NCHUNK; ++c) {
        const int idx = c * (D_DIM * N_DIM) + tid;
        const float a = ap[idx];
        const float b = hl[idx];
        ap[idx] = h;            // carry-in for phase 3
        h = fmaf(a, h, b);
    }
}

// ============ K_D: phase 3 — recompute with carry-in, fused epilogue =========
__global__ __launch_bounds__(256) void fm_scan_phase3(const float* __restrict__ dt,
                                                      const float* __restrict__ Bm,
                                                      const float* __restrict__ Cm,
                                                      const float* __restrict__ u,
                                                      const float* __restrict__ A_log,
                                                      const float* __restrict__ hstart,
                                                      const float* __restrict__ D_w,
                                                      const float* __restrict__ scale,
                                                      float* __restrict__ out) {
    const int t = threadIdx.x;
    const int c = blockIdx.x >> 2;
    const int d = ((blockIdx.x & 3) << 8) | t;
    float An[16];
#pragma unroll
    for (int n = 0; n < 16; ++n) An[n] = -__expf(A_log[n]);
    float h[16];
    const int base = c * (D_DIM * N_DIM) + d * 16;
    {
        float4 h0v = *(const float4*)&hstart[base + 0];
        float4 h1v = *(const float4*)&hstart[base + 4];
        float4 h2v = *(const float4*)&hstart[base + 8];
        float4 h3v = *(const float4*)&hstart[base + 12];
        h[0] = h0v.x; h[1] = h0v.y; h[2] = h0v.z; h[3] = h0v.w;
        h[4] = h1v.x; h[5] = h1v.y; h[6] = h1v.z; h[7] = h1v.w;
        h[8] = h2v.x; h[9] = h2v.y; h[10] = h2v.z; h[11] = h2v.w;
        h[12] = h3v.x; h[13] = h3v.y; h[14] = h3v.z; h[15] = h3v.w;
    }
    const float scl = fmaxf(scale[0], 0.5f);
    const float dw = D_w[d];
    const int l0 = c * T_CHUNK;
    for (int i = 0; i < T_CHUNK; ++i) {
        const int l = l0 + i;
        const float dtld = dt[l * D_DIM + d];
        const float uld  = u[l * D_DIM + d];
        const float4 b0 = *(const float4*)&Bm[l * 16 + 0];
        const float4 b1 = *(const float4*)&Bm[l * 16 + 4];
        const float4 b2 = *(const float4*)&Bm[l * 16 + 8];
        const float4 b3 = *(const float4*)&Bm[l * 16 + 12];
        const float4 c0 = *(const float4*)&Cm[l * 16 + 0];
        const float4 c1 = *(const float4*)&Cm[l * 16 + 4];
        const float4 c2 = *(const float4*)&Cm[l * 16 + 8];
        const float4 c3 = *(const float4*)&Cm[l * 16 + 12];
        float y = 0.f;
        auto body = [&](int n, float bn, float cn) {
            const float x = dtld * An[n];
            const float e = __expf(x);
            const float coef = (e - 1.f) * __builtin_amdgcn_rcpf(x + EPS_DISC);
            const float bu = coef * bn * uld;
            h[n] = fmaf(e, h[n], bu);
            y = fmaf(cn, h[n], y);
        };
        body(0, b0.x, c0.x);   body(1, b0.y, c0.y);   body(2, b0.z, c0.z);   body(3, b0.w, c0.w);
        body(4, b1.x, c1.x);   body(5, b1.y, c1.y);   body(6, b1.z, c1.z);   body(7, b1.w, c1.w);
        body(8, b2.x, c2.x);   body(9, b2.y, c2.y);   body(10, b2.z, c2.z);  body(11, b2.w, c2.w);
        body(12, b3.x, c3.x);  body(13, b3.y, c3.y);  body(14, b3.z, c3.z);  body(15, b3.w, c3.w);
        y = fmaf(dw, uld, y);
        out[l * D_DIM + d] = softplusf(y) * scl;
    }
}

extern "C" void kernel_launch(void* const* d_in, const int* in_sizes, int n_in,
                              void* d_out, int out_size, void* d_ws, size_t ws_size,
                              hipStream_t stream) {
    const float* u      = (const float*)d_in[0];
    const float* A_log  = (const float*)d_in[1];
    const float* dt_w   = (const float*)d_in[2];
    const float* dt_b   = (const float*)d_in[3];
    const float* B_w    = (const float*)d_in[4];
    const float* B_b    = (const float*)d_in[5];
    const float* C_w    = (const float*)d_in[6];
    const float* C_b    = (const float*)d_in[7];
    const float* D_w    = (const float*)d_in[8];
    const float* scale  = (const float*)d_in[9];
    const float* init_w = (const float*)d_in[10];
    const float* init_b = (const float*)d_in[11];
    float* out = (float*)d_out;

    float* ws = (float*)d_ws;
    float* dt = ws;                        // 2048*1024 = 2097152
    float* Bm = dt + 2097152;              // 32768
    float* Cm = Bm + 32768;                // 32768
    float* h0 = Cm + 32768;                // 16384
    float* ap = h0 + 16384;                // 64*16384 = 1048576
    float* hl = ap + 1048576;              // 1048576

    hipLaunchKernelGGL(fm_params, dim3(4480), dim3(256), 0, stream,
                       u, dt_w, dt_b, B_w, B_b, C_w, C_b, init_w, init_b,
                       dt, Bm, Cm, h0);
    hipLaunchKernelGGL(fm_scan_phase1, dim3(256), dim3(256), 0, stream, dt, Bm, u, A_log, ap, hl);
    hipLaunchKernelGGL(fm_scan_phase2, dim3(256), dim3(64), 0, stream, h0, ap, hl);
    hipLaunchKernelGGL(fm_scan_phase3, dim3(256), dim3(256), 0, stream, dt, Bm, Cm, u, A_log, ap, D_w, scale, out);
}